// Round 7
// baseline (185.158 us; speedup 1.0000x reference)
//
#include <hip/hip_runtime.h>
#include <hip/hip_bf16.h>
#include <float.h>

#define NTOK 8192   // B*G tokens
#define NCB  8192   // codebook entries
#define CDIM 256
#define KPTS 32
#define SQNT 24.0f  // i8 quantization scale
#define INV_CFOLD (SQNT * SQNT * 64.0f)   // d / CFOLD scale, CFOLD = 2/(S^2*128)

typedef __attribute__((ext_vector_type(8))) short short8;   // 8 bf16
typedef __attribute__((ext_vector_type(4))) float f32x4;
typedef __attribute__((ext_vector_type(4))) int i32x4;
typedef unsigned int u32;
typedef unsigned long long u64;

__device__ __forceinline__ void gl_lds16(const void* g, void* l) {
  __builtin_amdgcn_global_load_lds(
      (const __attribute__((address_space(1))) u32*)(g),
      (__attribute__((address_space(3))) u32*)(l), 16, 0, 0);
}

__device__ __forceinline__ ushort bf16_rne(float x) {
  u32 u = __float_as_uint(x);
  return (ushort)((u + 0x7fffu + ((u >> 16) & 1u)) >> 16);
}

__device__ __forceinline__ int pack4i8(int a, int b, int c, int d) {
  return (a & 0xff) | ((b & 0xff) << 8) | ((c & 0xff) << 16) | ((d & 0xff) << 24);
}

// ---------------- fused prep: i8 splits, cb bf16 frags, weights, cnorm ----
__global__ __launch_bounds__(256) void prep_k(
    const float* __restrict__ pf, const float* __restrict__ cb,
    const float* __restrict__ w1, const float* __restrict__ w2,
    const float* __restrict__ w3,
    i32x4* __restrict__ pf1, i32x4* __restrict__ pf2,
    i32x4* __restrict__ cb1, i32x4* __restrict__ cb2,
    ushort* __restrict__ cb_bf, ushort* __restrict__ w1s,
    ushort* __restrict__ w2s, ushort* __restrict__ w3s,
    float* __restrict__ cnorm) {
  int gid = blockIdx.x * 4 + (threadIdx.x >> 6);
  int lane = threadIdx.x & 63, r16 = lane & 15, quad = lane >> 4;
  if (gid < 4096) {
    bool is_cb = gid >= 2048;
    int t = is_cb ? gid - 2048 : gid;
    int tile = t >> 2, kb = t & 3;
    const float* src = is_cb ? cb : pf;
    int row = tile * 16 + r16;
    const float* sp = src + (size_t)row * CDIM + kb * 64 + quad * 16;
    float4 v0 = ((const float4*)sp)[0];
    float4 v1 = ((const float4*)sp)[1];
    float4 v2 = ((const float4*)sp)[2];
    float4 v3 = ((const float4*)sp)[3];
    float x[16] = {v0.x, v0.y, v0.z, v0.w, v1.x, v1.y, v1.z, v1.w,
                   v2.x, v2.y, v2.z, v2.w, v3.x, v3.y, v3.z, v3.w};
    int q1[16], q2[16];
    float s = 0.f;
#pragma unroll
    for (int e = 0; e < 16; e++) {
      float as = x[e] * SQNT;
      float a1 = rintf(as);
      a1 = fminf(fmaxf(a1, -127.f), 127.f);
      float a2 = rintf((as - a1) * 128.f);
      a2 = fminf(fmaxf(a2, -127.f), 127.f);
      q1[e] = (int)a1;
      q2[e] = (int)a2;
      s += x[e] * x[e];
    }
    i32x4 p1 = {pack4i8(q1[0], q1[1], q1[2], q1[3]),
                pack4i8(q1[4], q1[5], q1[6], q1[7]),
                pack4i8(q1[8], q1[9], q1[10], q1[11]),
                pack4i8(q1[12], q1[13], q1[14], q1[15])};
    i32x4 p2 = {pack4i8(q2[0], q2[1], q2[2], q2[3]),
                pack4i8(q2[4], q2[5], q2[6], q2[7]),
                pack4i8(q2[8], q2[9], q2[10], q2[11]),
                pack4i8(q2[12], q2[13], q2[14], q2[15])};
    size_t o = (size_t)t * 64 + lane;
    (is_cb ? cb1 : pf1)[o] = p1;
    (is_cb ? cb2 : pf2)[o] = p2;
    if (is_cb) {
      s += __shfl_xor(s, 16, 64);
      s += __shfl_xor(s, 32, 64);
      if (quad == 0) atomicAdd(cnorm + row, s);
    }
  } else if (gid < 8192) {
    int t = gid - 4096;
    int tile = t >> 3, kb = t & 7;
    int row = tile * 16 + r16;
    const float* sp = cb + (size_t)row * CDIM + kb * 32 + quad * 8;
    float4 a = ((const float4*)sp)[0];
    float4 b = ((const float4*)sp)[1];
    short8 vh = {(short)bf16_rne(a.x), (short)bf16_rne(a.y),
                 (short)bf16_rne(a.z), (short)bf16_rne(a.w),
                 (short)bf16_rne(b.x), (short)bf16_rne(b.y),
                 (short)bf16_rne(b.z), (short)bf16_rne(b.w)};
    *(short8*)(cb_bf + ((size_t)tile * 8 + kb) * 512 + lane * 8) = vh;
  } else if (gid < 8752) {
    int t = gid - 8192;
    const float* src;
    ushort* dst;
    int KB;
    if (t < 256)      { src = w1; dst = w1s; KB = 8; }
    else if (t < 512) { src = w2; dst = w2s; KB = 16; t -= 256; }
    else              { src = w3; dst = w3s; KB = 8;  t -= 512; }
    int tile = t / KB, kb = t - tile * KB, K = KB * 32;
    int row = tile * 16 + r16;
    const float* sp = src + (size_t)row * K + kb * 32 + quad * 8;
    float4 a = ((const float4*)sp)[0];
    float4 b = ((const float4*)sp)[1];
    short8 vh = {(short)bf16_rne(a.x), (short)bf16_rne(a.y),
                 (short)bf16_rne(a.z), (short)bf16_rne(a.w),
                 (short)bf16_rne(b.x), (short)bf16_rne(b.y),
                 (short)bf16_rne(b.z), (short)bf16_rne(b.w)};
    *(short8*)(dst + ((size_t)tile * KB + kb) * 512 + lane * 8) = vh;
  }
}

// -------- i8 MFMA distance GEMM + argmin, atomic-free, integer fold --------
// (byte-identical to R6)
__global__ __launch_bounds__(256, 2) void argmin_k(
    const char* __restrict__ A1g, const char* __restrict__ A2g,
    const char* __restrict__ B1g, const char* __restrict__ B2g,
    const float* __restrict__ cnorm, u64* __restrict__ pkeys) {
  __shared__ char lds[32 * 1024];
  int tid = threadIdx.x;
  int ns = blockIdx.x, mt = blockIdx.y;
  int wv = tid >> 6, lane = tid & 63;
  int quad = lane >> 4, r16 = lane & 15;
  int wr = wv >> 1, wc = wv & 1;

  int bvi[4][4], bii[4][4];
#pragma unroll
  for (int i = 0; i < 4; i++)
#pragma unroll
    for (int r = 0; r < 4; r++) { bvi[i][r] = 0x7fffffff; bii[i][r] = 0x7fffffff; }

  const char* bsrc = (wv == 0) ? A1g : (wv == 1) ? A2g : (wv == 2) ? B1g : B2g;

  for (int nts = 0; nts < 4; ++nts) {
    int nt = ns * 4 + nts;
    i32x4 am[4][4], ac[4][4];
#pragma unroll
    for (int i = 0; i < 4; i++)
#pragma unroll
      for (int j = 0; j < 4; j++) {
        am[i][j] = (i32x4){0, 0, 0, 0};
        ac[i][j] = (i32x4){0, 0, 0, 0};
      }
    for (int kb = 0; kb < 4; ++kb) {
#pragma unroll
      for (int u = 0; u < 8; ++u) {
        int gt = ((wv < 2) ? mt : nt) * 8 + u;
        gl_lds16(bsrc + ((size_t)gt * 4 + kb) * 1024 + lane * 16,
                 lds + (wv * 8 + u) * 1024);
      }
      __syncthreads();
      i32x4 f1[4], f2[4], g1[4], g2[4];
#pragma unroll
      for (int i = 0; i < 4; i++) {
        f1[i] = *(const i32x4*)(lds + (wr * 4 + i) * 1024 + lane * 16);
        f2[i] = *(const i32x4*)(lds + (8 + wr * 4 + i) * 1024 + lane * 16);
      }
#pragma unroll
      for (int j = 0; j < 4; j++) {
        g1[j] = *(const i32x4*)(lds + (16 + wc * 4 + j) * 1024 + lane * 16);
        g2[j] = *(const i32x4*)(lds + (24 + wc * 4 + j) * 1024 + lane * 16);
      }
#pragma unroll
      for (int i = 0; i < 4; i++)
#pragma unroll
        for (int j = 0; j < 4; j++) {
          am[i][j] = __builtin_amdgcn_mfma_i32_16x16x64_i8(f1[i], g1[j], am[i][j], 0, 0, 0);
          ac[i][j] = __builtin_amdgcn_mfma_i32_16x16x64_i8(f1[i], g2[j], ac[i][j], 0, 0, 0);
          ac[i][j] = __builtin_amdgcn_mfma_i32_16x16x64_i8(f2[i], g1[j], ac[i][j], 0, 0, 0);
        }
      __syncthreads();
    }
#pragma unroll
    for (int j = 0; j < 4; j++) {
      int col = nt * 128 + wc * 64 + j * 16 + r16;
      int cni = __float2int_rn(cnorm[col] * INV_CFOLD);
#pragma unroll
      for (int i = 0; i < 4; i++)
#pragma unroll
        for (int r = 0; r < 4; r++) {
          int di = cni - (am[i][j][r] * 128 + ac[i][j][r]);
          if (di < bvi[i][r]) { bvi[i][r] = di; bii[i][r] = col; }
        }
    }
  }
#pragma unroll
  for (int m = 1; m < 16; m <<= 1) {
#pragma unroll
    for (int i = 0; i < 4; i++)
#pragma unroll
      for (int r = 0; r < 4; r++) {
        int ov = __shfl_xor(bvi[i][r], m, 64);
        int oi = __shfl_xor(bii[i][r], m, 64);
        if (ov < bvi[i][r] || (ov == bvi[i][r] && oi < bii[i][r])) {
          bvi[i][r] = ov;
          bii[i][r] = oi;
        }
      }
  }
  if (r16 == 0) {
#pragma unroll
    for (int i = 0; i < 4; i++)
#pragma unroll
      for (int r = 0; r < 4; r++) {
        int row = mt * 128 + wr * 64 + i * 16 + quad * 4 + r;
        u32 mk = (u32)(bvi[i][r] + (1 << 30));
        pkeys[(size_t)(ns * 2 + wc) * NTOK + row] = ((u64)mk << 32) | (u32)bii[i][r];
      }
  }
}

// -------- fused MLP: 35-step double-buffered weight DMA pipeline --------
// 32 tokens/block, 256 blocks. Dynamic LDS (80 KB + tail):
//   [0,16K):   qs (gather) -> dead after fa1 preload; reused as h2
//   [16K,48K): h1          -> dead after unit 31; rec [16K,28K), gts [28K,40K)
//   [48K,80K): wbuf, 2 buffers x 16 KB; each = 2 jt-chunks x 8 KB (8 x 1 KB kb)
//   [80K,..):  ids[32], wsum[4]
// Units: 0..15 L1 (jt pair 2u,2u+1); 16..31 L2 (pair=(u-16)>>1, half=(u-16)&1);
//        32..34 L3. Wave (mtile=wv&1, p=wv>>1) computes jt = 2*step + p.
__global__ __launch_bounds__(256) void mlp_fused_k(
    const u64* __restrict__ pkeys, const ushort* __restrict__ cb_bf,
    const ushort* __restrict__ w1s, const float* __restrict__ b1,
    const ushort* __restrict__ w2s, const float* __restrict__ b2,
    const ushort* __restrict__ w3s, const float* __restrict__ b3,
    const float* __restrict__ neigh, float* __restrict__ out) {
  extern __shared__ char lds[];
  ushort* qsp = (ushort*)lds;
  ushort* h2p = (ushort*)lds;
  ushort* h1p = (ushort*)(lds + 16384);
  float* recp = (float*)(lds + 16384);
  float* gtsp = (float*)(lds + 28672);
  int* ids = (int*)(lds + 81920);
  float* wsum = (float*)(lds + 82048);

  int tid = threadIdx.x;
  int t0 = blockIdx.x * 32;
  int wv = tid >> 6, lane = tid & 63;
  int quad = lane >> 4, r16 = lane & 15;
  int mtile = wv & 1, p = wv >> 1;

  // ---- merge 32 key slots per row ----
  {
    int row_l = tid >> 3, sl = tid & 7;
    u64 best = ~0ull;
#pragma unroll
    for (int s = 0; s < 4; s++) {
      u64 v = pkeys[(size_t)(sl + s * 8) * NTOK + t0 + row_l];
      if (v < best) best = v;
    }
#pragma unroll
    for (int m = 1; m < 8; m <<= 1) {
      u64 o = __shfl_xor((unsigned long long)best, m, 64);
      if (o < best) best = o;
    }
    if (sl == 0) ids[row_l] = (int)(u32)best;
  }
  __syncthreads();

  // ---- gather quant A-frags from cb_bf into qs ----
  {
    int tile_l = wv >> 1, kb0 = (wv & 1) * 4;
    int id = ids[tile_l * 16 + r16];
#pragma unroll
    for (int q = 0; q < 4; q++) {
      int kb = kb0 + q;
      short8 v = *(const short8*)(cb_bf + ((size_t)(id >> 4) * 8 + kb) * 512 +
                                  (size_t)((id & 15) + quad * 16) * 8);
      *(short8*)(qsp + (size_t)(tile_l * 8 + kb) * 512 + lane * 8) = v;
    }
  }

  // stage unit helper: 16 x 1KB chunks, 4 per wave
  auto stage_unit = [&](int u) {
    char* dstbase = lds + 49152 + ((u & 1) << 14);
#pragma unroll
    for (int uu = 0; uu < 4; ++uu) {
      int c = wv + uu * 4;
      int pj = c >> 3, kb = c & 7;
      const ushort* src;
      if (u < 16) {
        src = w1s + (size_t)((2 * u + pj) * 8 + kb) * 512;
      } else if (u < 32) {
        int s2 = u - 16, pair = s2 >> 1, half = s2 & 1;
        src = w2s + (size_t)((2 * pair + pj) * 16 + half * 8 + kb) * 512;
      } else {
        int s3 = u - 32;
        src = w3s + (size_t)((2 * s3 + pj) * 8 + kb) * 512;
      }
      gl_lds16(src + lane * 8, dstbase + pj * 8192 + kb * 1024);
    }
  };

  stage_unit(0);
  __syncthreads();   // gather stores + unit-0 DMA complete

  // preload L1 A-fragments (qs dead afterwards)
  short8 fa1[8];
#pragma unroll
  for (int kb = 0; kb < 8; kb++)
    fa1[kb] = *(const short8*)(qsp + (size_t)(mtile * 8 + kb) * 512 + lane * 8);

  f32x4 acc2 = (f32x4){0.f, 0.f, 0.f, 0.f};
  for (int u = 0; u < 35; ++u) {
    if (u + 1 < 35) stage_unit(u + 1);
    const char* wb = lds + 49152 + ((u & 1) << 14) + p * 8192;
    if (u < 16) {
      // L1: 256 -> 512, relu
      int jt = 2 * u + p;
      f32x4 acc = (f32x4){0.f, 0.f, 0.f, 0.f};
#pragma unroll
      for (int q = 0; q < 8; q++) {
        short8 fb = *(const short8*)(wb + q * 1024 + lane * 16);
        acc = __builtin_amdgcn_mfma_f32_16x16x32_bf16(fa1[q], fb, acc, 0, 0, 0);
      }
      int col = jt * 16 + r16;
      float bj = b1[col];
#pragma unroll
      for (int reg = 0; reg < 4; reg++) {
        int row_l = mtile * 16 + quad * 4 + reg;
        float v = fmaxf(acc[reg] + bj, 0.f);
        size_t o = (size_t)((row_l >> 4) * 16 + (col >> 5)) * 512 +
                   (size_t)(((col >> 3) & 3) * 16 + (row_l & 15)) * 8 + (col & 7);
        h1p[o] = bf16_rne(v);
      }
    } else if (u < 32) {
      // L2: 512 -> 256, relu; acc carried across the two k-halves
      int s2 = u - 16, pair = s2 >> 1, half = s2 & 1;
      int jt = 2 * pair + p;
      if (half == 0) acc2 = (f32x4){0.f, 0.f, 0.f, 0.f};
#pragma unroll
      for (int q = 0; q < 8; q++) {
        short8 fa = *(const short8*)(h1p + (size_t)(mtile * 16 + half * 8 + q) * 512 + lane * 8);
        short8 fb = *(const short8*)(wb + q * 1024 + lane * 16);
        acc2 = __builtin_amdgcn_mfma_f32_16x16x32_bf16(fa, fb, acc2, 0, 0, 0);
      }
      if (half == 1) {
        int col = jt * 16 + r16;
        float bj = b2[col];
#pragma unroll
        for (int reg = 0; reg < 4; reg++) {
          int row_l = mtile * 16 + quad * 4 + reg;
          float v = fmaxf(acc2[reg] + bj, 0.f);
          size_t o = (size_t)((row_l >> 4) * 8 + (col >> 5)) * 512 +
                     (size_t)(((col >> 3) & 3) * 16 + (row_l & 15)) * 8 + (col & 7);
          h2p[o] = bf16_rne(v);
        }
      }
    } else {
      // L3: 256 -> 96 -> rec; plus gts staging (h1 dead)
      int s3 = u - 32;
      int jt = 2 * s3 + p;
      f32x4 acc = (f32x4){0.f, 0.f, 0.f, 0.f};
#pragma unroll
      for (int q = 0; q < 8; q++) {
        short8 fa = *(const short8*)(h2p + (size_t)(mtile * 8 + q) * 512 + lane * 8);
        short8 fb = *(const short8*)(wb + q * 1024 + lane * 16);
        acc = __builtin_amdgcn_mfma_f32_16x16x32_bf16(fa, fb, acc, 0, 0, 0);
      }
      int col = jt * 16 + r16;
      float bj = b3[col];
#pragma unroll
      for (int reg = 0; reg < 4; reg++) {
        int row_l = mtile * 16 + quad * 4 + reg;
        recp[(size_t)row_l * 96 + col] = acc[reg] + bj;
      }
      int idx = tid + s3 * 256;
      int t = idx / 24, c = (idx - t * 24) * 4;
      *(float4*)(gtsp + (size_t)t * 96 + c) =
          *(const float4*)(neigh + (size_t)(t0 + t) * 96 + c);
    }
    __syncthreads();
  }

  // ---- chamfer ----
  float local = 0.f;
#pragma unroll
  for (int pp = 0; pp < 4; ++pp) {
    int pidx = tid + pp * 256;
    int t = pidx >> 5, i = pidx & 31;
    float rx = recp[t * 96 + 3 * i], ry = recp[t * 96 + 3 * i + 1], rz = recp[t * 96 + 3 * i + 2];
    float gx = gtsp[t * 96 + 3 * i], gy = gtsp[t * 96 + 3 * i + 1], gz = gtsp[t * 96 + 3 * i + 2];
    float mA = FLT_MAX, mB = FLT_MAX;
#pragma unroll
    for (int j = 0; j < 32; j++) {
      float dx = rx - gtsp[t * 96 + 3 * j], dy = ry - gtsp[t * 96 + 3 * j + 1],
            dz = rz - gtsp[t * 96 + 3 * j + 2];
      float d = dx * dx + dy * dy + dz * dz;
      mA = fminf(mA, d);
      dx = recp[t * 96 + 3 * j] - gx; dy = recp[t * 96 + 3 * j + 1] - gy;
      dz = recp[t * 96 + 3 * j + 2] - gz;
      d = dx * dx + dy * dy + dz * dz;
      mB = fminf(mB, d);
    }
    local += mA + mB;
  }
#pragma unroll
  for (int off = 32; off; off >>= 1) local += __shfl_down(local, off, 64);
  if ((tid & 63) == 0) wsum[tid >> 6] = local;
  __syncthreads();
  if (tid == 0) {
    float s = wsum[0] + wsum[1] + wsum[2] + wsum[3];
    atomicAdd(out, s * (1.0f / (float)(NTOK * KPTS)));
  }
}

extern "C" void kernel_launch(void* const* d_in, const int* in_sizes, int n_in,
                              void* d_out, int out_size, void* d_ws, size_t ws_size,
                              hipStream_t stream) {
  const float* pf    = (const float*)d_in[0];
  const float* neigh = (const float*)d_in[1];
  const float* cb    = (const float*)d_in[2];
  const float* w1    = (const float*)d_in[3];
  const float* b1    = (const float*)d_in[4];
  const float* w2    = (const float*)d_in[5];
  const float* b2    = (const float*)d_in[6];
  const float* w3    = (const float*)d_in[7];
  const float* b3    = (const float*)d_in[8];
  float* out = (float*)d_out;
  char* base = (char*)d_ws;

  u64*   pkeys = (u64*)base;                       // 32*8192*8 = 2 MB
  float* cnorm = (float*)(base + 0x200000);        // 32 KB
  char*  pf1   = base + 0x210000;                  // 2 MB each
  char*  pf2   = base + 0x410000;
  char*  cb1   = base + 0x610000;
  char*  cb2   = base + 0x810000;
  ushort* cb_bf = (ushort*)(base + 0xA10000);      // 4 MB
  ushort* w1s   = (ushort*)(base + 0xE10000);      // 256 KB
  ushort* w2s   = (ushort*)(base + 0xE50000);      // 256 KB
  ushort* w3s   = (ushort*)(base + 0xE90000);      // 48 KB

  hipMemsetAsync(d_out, 0, sizeof(float), stream);
  hipMemsetAsync(cnorm, 0, NCB * sizeof(float), stream);
  prep_k<<<2188, 256, 0, stream>>>(pf, cb, w1, w2, w3,
                                   (i32x4*)pf1, (i32x4*)pf2, (i32x4*)cb1,
                                   (i32x4*)cb2, cb_bf, w1s, w2s, w3s, cnorm);
  argmin_k<<<dim3(16, 64), 256, 0, stream>>>(pf1, pf2, cb1, cb2, cnorm, pkeys);
  mlp_fused_k<<<256, 256, 82176, stream>>>(pkeys, cb_bf, w1s, b1, w2s, b2,
                                           w3s, b3, neigh, out);
}

// Round 8
// 166.953 us; speedup vs baseline: 1.1090x; 1.1090x over previous
//
#include <hip/hip_runtime.h>
#include <hip/hip_bf16.h>
#include <float.h>

#define NTOK 8192   // B*G tokens
#define NCB  8192   // codebook entries
#define CDIM 256
#define KPTS 32
#define SQNT 24.0f  // i8 quantization scale
#define INV_CFOLD (SQNT * SQNT * 64.0f)   // d / CFOLD scale, CFOLD = 2/(S^2*128)

typedef __attribute__((ext_vector_type(8))) short short8;   // 8 bf16
typedef __attribute__((ext_vector_type(4))) float f32x4;
typedef __attribute__((ext_vector_type(4))) int i32x4;
typedef unsigned int u32;
typedef unsigned long long u64;

__device__ __forceinline__ void gl_lds16(const void* g, void* l) {
  __builtin_amdgcn_global_load_lds(
      (const __attribute__((address_space(1))) u32*)(g),
      (__attribute__((address_space(3))) u32*)(l), 16, 0, 0);
}

__device__ __forceinline__ ushort bf16_rne(float x) {
  u32 u = __float_as_uint(x);
  return (ushort)((u + 0x7fffu + ((u >> 16) & 1u)) >> 16);
}

__device__ __forceinline__ int pack4i8(int a, int b, int c, int d) {
  return (a & 0xff) | ((b & 0xff) << 8) | ((c & 0xff) << 16) | ((d & 0xff) << 24);
}

// ---------------- fused prep: i8 splits, cb bf16 frags, weights, cnorm ----
__global__ __launch_bounds__(256) void prep_k(
    const float* __restrict__ pf, const float* __restrict__ cb,
    const float* __restrict__ w1, const float* __restrict__ w2,
    const float* __restrict__ w3,
    i32x4* __restrict__ pf1, i32x4* __restrict__ pf2,
    i32x4* __restrict__ cb1, i32x4* __restrict__ cb2,
    ushort* __restrict__ cb_bf, ushort* __restrict__ w1s,
    ushort* __restrict__ w2s, ushort* __restrict__ w3s,
    float* __restrict__ cnorm) {
  int gid = blockIdx.x * 4 + (threadIdx.x >> 6);
  int lane = threadIdx.x & 63, r16 = lane & 15, quad = lane >> 4;
  if (gid < 4096) {
    bool is_cb = gid >= 2048;
    int t = is_cb ? gid - 2048 : gid;
    int tile = t >> 2, kb = t & 3;
    const float* src = is_cb ? cb : pf;
    int row = tile * 16 + r16;
    const float* sp = src + (size_t)row * CDIM + kb * 64 + quad * 16;
    float4 v0 = ((const float4*)sp)[0];
    float4 v1 = ((const float4*)sp)[1];
    float4 v2 = ((const float4*)sp)[2];
    float4 v3 = ((const float4*)sp)[3];
    float x[16] = {v0.x, v0.y, v0.z, v0.w, v1.x, v1.y, v1.z, v1.w,
                   v2.x, v2.y, v2.z, v2.w, v3.x, v3.y, v3.z, v3.w};
    int q1[16], q2[16];
    float s = 0.f;
#pragma unroll
    for (int e = 0; e < 16; e++) {
      float as = x[e] * SQNT;
      float a1 = rintf(as);
      a1 = fminf(fmaxf(a1, -127.f), 127.f);
      float a2 = rintf((as - a1) * 128.f);
      a2 = fminf(fmaxf(a2, -127.f), 127.f);
      q1[e] = (int)a1;
      q2[e] = (int)a2;
      s += x[e] * x[e];
    }
    i32x4 p1 = {pack4i8(q1[0], q1[1], q1[2], q1[3]),
                pack4i8(q1[4], q1[5], q1[6], q1[7]),
                pack4i8(q1[8], q1[9], q1[10], q1[11]),
                pack4i8(q1[12], q1[13], q1[14], q1[15])};
    i32x4 p2 = {pack4i8(q2[0], q2[1], q2[2], q2[3]),
                pack4i8(q2[4], q2[5], q2[6], q2[7]),
                pack4i8(q2[8], q2[9], q2[10], q2[11]),
                pack4i8(q2[12], q2[13], q2[14], q2[15])};
    size_t o = (size_t)t * 64 + lane;
    (is_cb ? cb1 : pf1)[o] = p1;
    (is_cb ? cb2 : pf2)[o] = p2;
    if (is_cb) {
      s += __shfl_xor(s, 16, 64);
      s += __shfl_xor(s, 32, 64);
      if (quad == 0) atomicAdd(cnorm + row, s);
    }
  } else if (gid < 8192) {
    int t = gid - 4096;
    int tile = t >> 3, kb = t & 7;
    int row = tile * 16 + r16;
    const float* sp = cb + (size_t)row * CDIM + kb * 32 + quad * 8;
    float4 a = ((const float4*)sp)[0];
    float4 b = ((const float4*)sp)[1];
    short8 vh = {(short)bf16_rne(a.x), (short)bf16_rne(a.y),
                 (short)bf16_rne(a.z), (short)bf16_rne(a.w),
                 (short)bf16_rne(b.x), (short)bf16_rne(b.y),
                 (short)bf16_rne(b.z), (short)bf16_rne(b.w)};
    *(short8*)(cb_bf + ((size_t)tile * 8 + kb) * 512 + lane * 8) = vh;
  } else if (gid < 8752) {
    int t = gid - 8192;
    const float* src;
    ushort* dst;
    int KB;
    if (t < 256)      { src = w1; dst = w1s; KB = 8; }
    else if (t < 512) { src = w2; dst = w2s; KB = 16; t -= 256; }
    else              { src = w3; dst = w3s; KB = 8;  t -= 512; }
    int tile = t / KB, kb = t - tile * KB, K = KB * 32;
    int row = tile * 16 + r16;
    const float* sp = src + (size_t)row * K + kb * 32 + quad * 8;
    float4 a = ((const float4*)sp)[0];
    float4 b = ((const float4*)sp)[1];
    short8 vh = {(short)bf16_rne(a.x), (short)bf16_rne(a.y),
                 (short)bf16_rne(a.z), (short)bf16_rne(a.w),
                 (short)bf16_rne(b.x), (short)bf16_rne(b.y),
                 (short)bf16_rne(b.z), (short)bf16_rne(b.w)};
    *(short8*)(dst + ((size_t)tile * KB + kb) * 512 + lane * 8) = vh;
  }
}

// -------- i8 MFMA distance GEMM + argmin, double-buffered staging --------
// Flattened stage loop s = nts*4 + kb; stage s+1 into buf[(s+1)&1] BEFORE
// computing s from buf[s&1]; single barrier per stage -> DMA overlaps MFMA.
__global__ __launch_bounds__(256, 2) void argmin_k(
    const char* __restrict__ A1g, const char* __restrict__ A2g,
    const char* __restrict__ B1g, const char* __restrict__ B2g,
    const float* __restrict__ cnorm, u64* __restrict__ pkeys) {
  __shared__ char lds[2][32768];
  int tid = threadIdx.x;
  int ns = blockIdx.x, mt = blockIdx.y;
  int wv = tid >> 6, lane = tid & 63;
  int quad = lane >> 4, r16 = lane & 15;
  int wr = wv >> 1, wc = wv & 1;

  int bvi[4][4], bii[4][4];
#pragma unroll
  for (int i = 0; i < 4; i++)
#pragma unroll
    for (int r = 0; r < 4; r++) { bvi[i][r] = 0x7fffffff; bii[i][r] = 0x7fffffff; }

  const char* bsrc = (wv == 0) ? A1g : (wv == 1) ? A2g : (wv == 2) ? B1g : B2g;

  i32x4 am[4][4], ac[4][4];

  auto stage = [&](int s) {
    int nts = s >> 2, kb = s & 3;
    int nt = ns * 4 + nts;
    char* dst = lds[s & 1] + wv * 8192;
    int gt0 = ((wv < 2) ? mt : nt) * 8;
#pragma unroll
    for (int u = 0; u < 8; ++u)
      gl_lds16(bsrc + ((size_t)(gt0 + u) * 4 + kb) * 1024 + lane * 16,
               dst + u * 1024);
  };

  stage(0);
  __syncthreads();
  for (int s = 0; s < 16; ++s) {
    int kb = s & 3, nts = s >> 2;
    if (kb == 0) {
#pragma unroll
      for (int i = 0; i < 4; i++)
#pragma unroll
        for (int j = 0; j < 4; j++) {
          am[i][j] = (i32x4){0, 0, 0, 0};
          ac[i][j] = (i32x4){0, 0, 0, 0};
        }
    }
    if (s < 15) stage(s + 1);
    const char* L = lds[s & 1];
    i32x4 f1[4], f2[4], g1[4], g2[4];
#pragma unroll
    for (int i = 0; i < 4; i++) {
      f1[i] = *(const i32x4*)(L + (wr * 4 + i) * 1024 + lane * 16);
      f2[i] = *(const i32x4*)(L + (8 + wr * 4 + i) * 1024 + lane * 16);
    }
#pragma unroll
    for (int j = 0; j < 4; j++) {
      g1[j] = *(const i32x4*)(L + (16 + wc * 4 + j) * 1024 + lane * 16);
      g2[j] = *(const i32x4*)(L + (24 + wc * 4 + j) * 1024 + lane * 16);
    }
#pragma unroll
    for (int i = 0; i < 4; i++)
#pragma unroll
      for (int j = 0; j < 4; j++) {
        am[i][j] = __builtin_amdgcn_mfma_i32_16x16x64_i8(f1[i], g1[j], am[i][j], 0, 0, 0);
        ac[i][j] = __builtin_amdgcn_mfma_i32_16x16x64_i8(f1[i], g2[j], ac[i][j], 0, 0, 0);
        ac[i][j] = __builtin_amdgcn_mfma_i32_16x16x64_i8(f2[i], g1[j], ac[i][j], 0, 0, 0);
      }
    if (kb == 3) {
      int nt = ns * 4 + nts;
#pragma unroll
      for (int j = 0; j < 4; j++) {
        int col = nt * 128 + wc * 64 + j * 16 + r16;
        int cni = __float2int_rn(cnorm[col] * INV_CFOLD);
#pragma unroll
        for (int i = 0; i < 4; i++)
#pragma unroll
          for (int r = 0; r < 4; r++) {
            int di = cni - (am[i][j][r] * 128 + ac[i][j][r]);
            if (di < bvi[i][r]) { bvi[i][r] = di; bii[i][r] = col; }
          }
      }
    }
    __syncthreads();
  }
#pragma unroll
  for (int m = 1; m < 16; m <<= 1) {
#pragma unroll
    for (int i = 0; i < 4; i++)
#pragma unroll
      for (int r = 0; r < 4; r++) {
        int ov = __shfl_xor(bvi[i][r], m, 64);
        int oi = __shfl_xor(bii[i][r], m, 64);
        if (ov < bvi[i][r] || (ov == bvi[i][r] && oi < bii[i][r])) {
          bvi[i][r] = ov;
          bii[i][r] = oi;
        }
      }
  }
  if (r16 == 0) {
#pragma unroll
    for (int i = 0; i < 4; i++)
#pragma unroll
      for (int r = 0; r < 4; r++) {
        int row = mt * 128 + wr * 64 + i * 16 + quad * 4 + r;
        u32 mk = (u32)(bvi[i][r] + (1 << 30));
        pkeys[(size_t)(ns * 2 + wc) * NTOK + row] = ((u64)mk << 32) | (u32)bii[i][r];
      }
  }
}

// -------- fused MLP: 16 tokens/block, 512 blocks x 512 threads (8 waves) ----
// R6 structure (weights global->VGPR), 4x the wave-level latency hiding.
__global__ __launch_bounds__(512) void mlp_fused_k(
    const u64* __restrict__ pkeys, const ushort* __restrict__ cb_bf,
    const ushort* __restrict__ w1s, const float* __restrict__ b1,
    const ushort* __restrict__ w2s, const float* __restrict__ b2,
    const ushort* __restrict__ w3s, const float* __restrict__ b3,
    const float* __restrict__ neigh, float* __restrict__ out) {
  __shared__ ushort qs_h2[8 * 512];   // qs, reused as h2 after L1 preload
  __shared__ ushort h1s[16 * 512];
  __shared__ float rec[16 * 96];
  __shared__ float gts[16 * 96];
  __shared__ int ids[16];
  __shared__ float wsum[8];

  int tid = threadIdx.x;
  int t0 = blockIdx.x * 16;
  int wv = tid >> 6, lane = tid & 63;
  int quad = lane >> 4, r16 = lane & 15;

  // ---- merge 32 key slots per row: 16 rows x 32 threads ----
  {
    int row_l = tid >> 5, sl = tid & 31;
    u64 best = pkeys[(size_t)sl * NTOK + t0 + row_l];
#pragma unroll
    for (int m = 1; m < 32; m <<= 1) {
      u64 o = __shfl_xor((unsigned long long)best, m, 64);
      if (o < best) best = o;
    }
    if (sl == 0) ids[row_l] = (int)(u32)best;
  }
  __syncthreads();

  // ---- gather quant A-frags from cb_bf (wave wv handles kb=wv) ----
  {
    int kb = wv;
    int id = ids[r16];
    short8 v = *(const short8*)(cb_bf + ((size_t)(id >> 4) * 8 + kb) * 512 +
                                (size_t)((id & 15) + quad * 16) * 8);
    *(short8*)(qs_h2 + (size_t)kb * 512 + lane * 8) = v;
  }
  __syncthreads();

  // preload L1 A-fragments (qs dead afterwards)
  short8 fa1[8];
#pragma unroll
  for (int kb = 0; kb < 8; kb++)
    fa1[kb] = *(const short8*)(qs_h2 + (size_t)kb * 512 + lane * 8);
  __syncthreads();

  // ---- layer 1: 256 -> 512, relu. 32 jt over 8 waves ----
#pragma unroll
  for (int jj = 0; jj < 4; ++jj) {
    int jt = wv + jj * 8;
    f32x4 acc = (f32x4){0.f, 0.f, 0.f, 0.f};
#pragma unroll
    for (int kb = 0; kb < 8; kb++) {
      short8 fb = *(const short8*)(w1s + ((size_t)jt * 8 + kb) * 512 + lane * 8);
      acc = __builtin_amdgcn_mfma_f32_16x16x32_bf16(fa1[kb], fb, acc, 0, 0, 0);
    }
    int col = jt * 16 + r16;
    float bj = b1[col];
#pragma unroll
    for (int reg = 0; reg < 4; reg++) {
      int row_l = quad * 4 + reg;
      float v = fmaxf(acc[reg] + bj, 0.f);
      size_t o = (size_t)(col >> 5) * 512 +
                 (size_t)(((col >> 3) & 3) * 16 + row_l) * 8 + (col & 7);
      h1s[o] = bf16_rne(v);
    }
  }
  __syncthreads();

  // ---- layer 2: 512 -> 256, relu. 16 jt over 8 waves ----
#pragma unroll
  for (int jj = 0; jj < 2; ++jj) {
    int jt = wv + jj * 8;
    f32x4 acc = (f32x4){0.f, 0.f, 0.f, 0.f};
#pragma unroll
    for (int kb = 0; kb < 16; kb++) {
      short8 fa = *(const short8*)(h1s + (size_t)kb * 512 + lane * 8);
      short8 fb = *(const short8*)(w2s + ((size_t)jt * 16 + kb) * 512 + lane * 8);
      acc = __builtin_amdgcn_mfma_f32_16x16x32_bf16(fa, fb, acc, 0, 0, 0);
    }
    int col = jt * 16 + r16;
    float bj = b2[col];
#pragma unroll
    for (int reg = 0; reg < 4; reg++) {
      int row_l = quad * 4 + reg;
      float v = fmaxf(acc[reg] + bj, 0.f);
      size_t o = (size_t)(col >> 5) * 512 +
                 (size_t)(((col >> 3) & 3) * 16 + row_l) * 8 + (col & 7);
      qs_h2[o] = bf16_rne(v);
    }
  }
  __syncthreads();

  // ---- stage ground truth ----
  if (tid < 384) {
    int t = tid / 24, c = (tid - t * 24) * 4;
    *(float4*)(gts + (size_t)t * 96 + c) =
        *(const float4*)(neigh + (size_t)(t0 + t) * 96 + c);
  }

  // ---- layer 3: 256 -> 96. 6 jt over waves 0..5 ----
  if (wv < 6) {
    int jt = wv;
    f32x4 acc = (f32x4){0.f, 0.f, 0.f, 0.f};
#pragma unroll
    for (int kb = 0; kb < 8; kb++) {
      short8 fa = *(const short8*)(qs_h2 + (size_t)kb * 512 + lane * 8);
      short8 fb = *(const short8*)(w3s + ((size_t)jt * 8 + kb) * 512 + lane * 8);
      acc = __builtin_amdgcn_mfma_f32_16x16x32_bf16(fa, fb, acc, 0, 0, 0);
    }
    int col = jt * 16 + r16;
    float bj = b3[col];
#pragma unroll
    for (int reg = 0; reg < 4; reg++) {
      int row_l = quad * 4 + reg;
      rec[(size_t)row_l * 96 + col] = acc[reg] + bj;
    }
  }
  __syncthreads();

  // ---- chamfer: 512 point-slots, 1 per thread ----
  float local = 0.f;
  {
    int t = tid >> 5, i = tid & 31;
    float rx = rec[t * 96 + 3 * i], ry = rec[t * 96 + 3 * i + 1], rz = rec[t * 96 + 3 * i + 2];
    float gx = gts[t * 96 + 3 * i], gy = gts[t * 96 + 3 * i + 1], gz = gts[t * 96 + 3 * i + 2];
    float mA = FLT_MAX, mB = FLT_MAX;
#pragma unroll
    for (int j = 0; j < 32; j++) {
      float dx = rx - gts[t * 96 + 3 * j], dy = ry - gts[t * 96 + 3 * j + 1],
            dz = rz - gts[t * 96 + 3 * j + 2];
      float d = dx * dx + dy * dy + dz * dz;
      mA = fminf(mA, d);
      dx = rec[t * 96 + 3 * j] - gx; dy = rec[t * 96 + 3 * j + 1] - gy;
      dz = rec[t * 96 + 3 * j + 2] - gz;
      d = dx * dx + dy * dy + dz * dz;
      mB = fminf(mB, d);
    }
    local = mA + mB;
  }
#pragma unroll
  for (int off = 32; off; off >>= 1) local += __shfl_down(local, off, 64);
  if (lane == 0) wsum[wv] = local;
  __syncthreads();
  if (tid == 0) {
    float s = 0.f;
#pragma unroll
    for (int w = 0; w < 8; w++) s += wsum[w];
    atomicAdd(out, s * (1.0f / (float)(NTOK * KPTS)));
  }
}

extern "C" void kernel_launch(void* const* d_in, const int* in_sizes, int n_in,
                              void* d_out, int out_size, void* d_ws, size_t ws_size,
                              hipStream_t stream) {
  const float* pf    = (const float*)d_in[0];
  const float* neigh = (const float*)d_in[1];
  const float* cb    = (const float*)d_in[2];
  const float* w1    = (const float*)d_in[3];
  const float* b1    = (const float*)d_in[4];
  const float* w2    = (const float*)d_in[5];
  const float* b2    = (const float*)d_in[6];
  const float* w3    = (const float*)d_in[7];
  const float* b3    = (const float*)d_in[8];
  float* out = (float*)d_out;
  char* base = (char*)d_ws;

  u64*   pkeys = (u64*)base;                       // 32*8192*8 = 2 MB
  float* cnorm = (float*)(base + 0x200000);        // 32 KB
  char*  pf1   = base + 0x210000;                  // 2 MB each
  char*  pf2   = base + 0x410000;
  char*  cb1   = base + 0x610000;
  char*  cb2   = base + 0x810000;
  ushort* cb_bf = (ushort*)(base + 0xA10000);      // 4 MB
  ushort* w1s   = (ushort*)(base + 0xE10000);      // 256 KB
  ushort* w2s   = (ushort*)(base + 0xE50000);      // 256 KB
  ushort* w3s   = (ushort*)(base + 0xE90000);      // 48 KB

  hipMemsetAsync(d_out, 0, sizeof(float), stream);
  hipMemsetAsync(cnorm, 0, NCB * sizeof(float), stream);
  prep_k<<<2188, 256, 0, stream>>>(pf, cb, w1, w2, w3,
                                   (i32x4*)pf1, (i32x4*)pf2, (i32x4*)cb1,
                                   (i32x4*)cb2, cb_bf, w1s, w2s, w3s, cnorm);
  argmin_k<<<dim3(16, 64), 256, 0, stream>>>(pf1, pf2, cb1, cb2, cnorm, pkeys);
  mlp_fused_k<<<512, 512, 0, stream>>>(pkeys, cb_bf, w1s, b1, w2s, b2,
                                       w3s, b3, neigh, out);
}